// Round 2
// baseline (281.701 us; speedup 1.0000x reference)
//
#include <hip/hip_runtime.h>
#include <hip/hip_bf16.h>
#include <math.h>

typedef __attribute__((ext_vector_type(8))) short bf16x8;
typedef __attribute__((ext_vector_type(4))) float f32x4;

__device__ inline short f2bf(float f) {
    union { float f; unsigned u; } x; x.f = f;
    unsigned r = (x.u + 0x7FFFu + ((x.u >> 16) & 1u)) >> 16;
    return (short)r;
}

__device__ inline float fast_exp2(float x) {
#if __has_builtin(__builtin_amdgcn_exp2f)
    return __builtin_amdgcn_exp2f(x);
#else
    return exp2f(x);
#endif
}

// ---------------------------------------------------------------------------
// Kernel 1: qkv = array(4096x256) @ Wqkv(256x3072), output split to
// Q/K/V bf16 buffers in (B,H,N,64) layout.  (unchanged this round)
// ---------------------------------------------------------------------------
__global__ __launch_bounds__(256) void qkv_kernel(
        const float* __restrict__ A, const float* __restrict__ W,
        short* __restrict__ Qb, short* __restrict__ Kb, short* __restrict__ Vb) {
    __shared__ short As[64 * 40];
    __shared__ short Bs[64 * 40];
    int m0 = blockIdx.x * 64;
    int n0 = blockIdx.y * 64;
    int t = threadIdx.x;
    int wave = t >> 6, lane = t & 63;
    int quad = lane >> 4, l16 = lane & 15;
    f32x4 acc[4] = {};
    for (int k0 = 0; k0 < 256; k0 += 32) {
        __syncthreads();
        {
            int i = t * 8;
            int row = i >> 5, col = i & 31;
            const float* src = A + (m0 + row) * 256 + k0 + col;
            short* dst = &As[row * 40 + col];
#pragma unroll
            for (int j = 0; j < 8; ++j) dst[j] = f2bf(src[j]);
        }
        {
            int i = t * 8;
            int kr = i >> 6, col = i & 63;
            const float* src = W + (k0 + kr) * 3072 + n0 + col;
#pragma unroll
            for (int j = 0; j < 8; ++j) Bs[(col + j) * 40 + kr] = f2bf(src[j]);
        }
        __syncthreads();
        bf16x8 af = *(const bf16x8*)&As[(wave * 16 + l16) * 40 + quad * 8];
#pragma unroll
        for (int c = 0; c < 4; ++c) {
            bf16x8 bfr = *(const bf16x8*)&Bs[(c * 16 + l16) * 40 + quad * 8];
            acc[c] = __builtin_amdgcn_mfma_f32_16x16x32_bf16(af, bfr, acc[c], 0, 0, 0);
        }
    }
#pragma unroll
    for (int c = 0; c < 4; ++c) {
#pragma unroll
        for (int r = 0; r < 4; ++r) {
            int gm = m0 + wave * 16 + quad * 4 + r;
            int gc = n0 + c * 16 + l16;
            int b = gm >> 11, n = gm & 2047;
            int sel = gc >> 10, within = gc & 1023;
            int h = within >> 6, dim = within & 63;
            short* dst = (sel == 0) ? Qb : ((sel == 1) ? Kb : Vb);
            dst[(((b * 16 + h) * 2048 + n) << 6) + dim] = f2bf(acc[c][r]);
        }
    }
}

// ---------------------------------------------------------------------------
// Kernel 2: flash attention, S^T formulation.
//   S^T = K(permuted rows) @ Q^T via mfma(A=kf, B=qf) -> lane holds
//   P[q=l16][key=quad*8+j] after exp, which IS the A-fragment for PV.
//   V staged transposed in LDS (pad 72), double-buffered, 1 barrier/iter.
// ---------------------------------------------------------------------------
#define VP 72
__global__ __launch_bounds__(256, 4) void attn_kernel(
        const short* __restrict__ Qb, const short* __restrict__ Kb,
        const short* __restrict__ Vb, short* __restrict__ AO) {
    __shared__ short VT[2][64 * VP];     // VT[buf][d][key]
    int bh = blockIdx.y;
    int qt = blockIdx.x;
    int b = bh >> 4, h = bh & 15;
    int t = threadIdx.x, wave = t >> 6, lane = t & 63;
    int quad = lane >> 4, l16 = lane & 15;
    const short* Qp = Qb + (size_t)bh * 2048 * 64;
    const short* Kp = Kb + (size_t)bh * 2048 * 64;
    const short* Vp = Vb + (size_t)bh * 2048 * 64;
    int q0 = qt * 64 + wave * 16;
    bf16x8 qf0 = *(const bf16x8*)&Qp[(q0 + l16) * 64 + quad * 8];
    bf16x8 qf1 = *(const bf16x8*)&Qp[(q0 + l16) * 64 + 32 + quad * 8];
    f32x4 o[4] = {};
    float m_run = -1e30f, l_run = 0.f;
    const float SC = 0.18033688011112042f;   // 0.125 * log2(e)

    // stage V tile kt (64 keys x 64 dims) transposed into VT[buf][d][key]
    // thread t: keys {2*(t&31), +1}, dims (t>>5)*8 .. +7; dword-pair writes.
    auto stage = [&](int kt, int buf) {
        int key = (t & 31) * 2;
        int d0 = (t >> 5) * 8;
        const short* s0 = Vp + ((kt * 64 + key) << 6) + d0;
        bf16x8 r0 = *(const bf16x8*)s0;
        bf16x8 r1 = *(const bf16x8*)(s0 + 64);
        short* base = &VT[buf][0];
#pragma unroll
        for (int j = 0; j < 8; ++j) {
            unsigned pk = ((unsigned)(unsigned short)r0[j]) |
                          (((unsigned)(unsigned short)r1[j]) << 16);
            *(unsigned*)&base[(d0 + j) * VP + key] = pk;
        }
    };

    stage(0, 0);
    for (int kt = 0; kt < 32; ++kt) {
        __syncthreads();
        if (kt + 1 < 32) stage(kt + 1, (kt + 1) & 1);
        const short* vt = &VT[kt & 1][0];

        // S^T: 4 mfma-pairs; permuted key map so C rows = keys quad*8+r (+4)
        f32x4 s[4];
#pragma unroll
        for (int hh = 0; hh < 2; ++hh) {
#pragma unroll
            for (int ab = 0; ab < 2; ++ab) {
                int keyl = hh * 32 + ((l16 >> 2) * 8) + (l16 & 3) + ab * 4;
                const short* kp = Kp + ((kt * 64 + keyl) << 6) + quad * 8;
                bf16x8 kf0 = *(const bf16x8*)kp;
                bf16x8 kf1 = *(const bf16x8*)(kp + 32);
                f32x4 z = {};
                z = __builtin_amdgcn_mfma_f32_16x16x32_bf16(kf0, qf0, z, 0, 0, 0);
                z = __builtin_amdgcn_mfma_f32_16x16x32_bf16(kf1, qf1, z, 0, 0, 0);
                s[hh * 2 + ab] = z;
            }
        }
        // online softmax (query = l16, keys spread over quad + regs)
        float mt = -1e30f;
#pragma unroll
        for (int i = 0; i < 4; ++i)
#pragma unroll
            for (int r = 0; r < 4; ++r) mt = fmaxf(mt, s[i][r]);
        mt = fmaxf(mt, __shfl_xor(mt, 16, 64));
        mt = fmaxf(mt, __shfl_xor(mt, 32, 64));
        float mn = fmaxf(m_run, mt);
        float alpha = fast_exp2((m_run - mn) * SC);
        m_run = mn;

        float sum = 0.f;
        bf16x8 pa[2];
#pragma unroll
        for (int hh = 0; hh < 2; ++hh) {
#pragma unroll
            for (int ab = 0; ab < 2; ++ab) {
#pragma unroll
                for (int r = 0; r < 4; ++r) {
                    float p = fast_exp2((s[hh * 2 + ab][r] - mn) * SC);
                    sum += p;
                    pa[hh][ab * 4 + r] = f2bf(p);
                }
            }
        }
        sum += __shfl_xor(sum, 16, 64);
        sum += __shfl_xor(sum, 32, 64);
        l_run = l_run * alpha + sum;

        // rescale O (O rows = quad*4+r => need alpha of query quad*4+r)
        float alphaT[4];
#pragma unroll
        for (int r = 0; r < 4; ++r) alphaT[r] = __shfl(alpha, quad * 4 + r, 64);
#pragma unroll
        for (int dt = 0; dt < 4; ++dt)
#pragma unroll
            for (int r = 0; r < 4; ++r) o[dt][r] *= alphaT[r];

        // O += P @ V  (pa is A-fragment; V^T b128 reads are bank-optimal)
#pragma unroll
        for (int hh = 0; hh < 2; ++hh) {
#pragma unroll
            for (int dt = 0; dt < 4; ++dt) {
                bf16x8 vb = *(const bf16x8*)&vt[(dt * 16 + l16) * VP + hh * 32 + quad * 8];
                o[dt] = __builtin_amdgcn_mfma_f32_16x16x32_bf16(pa[hh], vb, o[dt], 0, 0, 0);
            }
        }
    }
    // epilogue
    float rT[4];
#pragma unroll
    for (int r = 0; r < 4; ++r) {
        float lT = __shfl(l_run, quad * 4 + r, 64);
        rT[r] = 1.0f / lT;
    }
#pragma unroll
    for (int dt = 0; dt < 4; ++dt) {
#pragma unroll
        for (int r = 0; r < 4; ++r) {
            float val = o[dt][r] * rT[r];
            int qrow = q0 + quad * 4 + r;
            AO[((size_t)(b * 2048 + qrow) << 10) + h * 64 + dt * 16 + l16] = f2bf(val);
        }
    }
}

// ---------------------------------------------------------------------------
// Kernel 3: out = AO(4096x1024 bf16) @ Wout(1024x64) -> fp32. (unchanged)
// ---------------------------------------------------------------------------
__global__ __launch_bounds__(128) void out_kernel(
        const short* __restrict__ AO, const float* __restrict__ Wout,
        float* __restrict__ Out) {
    __shared__ short As[32 * 40];
    __shared__ short Bs[64 * 40];
    int m0 = blockIdx.x * 32;
    int t = threadIdx.x, wave = t >> 6, lane = t & 63;
    int quad = lane >> 4, l16 = lane & 15;
    f32x4 acc[4] = {};
    for (int k0 = 0; k0 < 1024; k0 += 32) {
        __syncthreads();
        {
            int i = t * 8, row = i >> 5, col = i & 31;
            const short* src = AO + (size_t)(m0 + row) * 1024 + k0 + col;
            *(bf16x8*)&As[row * 40 + col] = *(const bf16x8*)src;
        }
        {
            int i = t * 16, kr = i >> 6, col = i & 63;
            const float* src = Wout + (k0 + kr) * 64 + col;
#pragma unroll
            for (int j = 0; j < 16; ++j) Bs[(col + j) * 40 + kr] = f2bf(src[j]);
        }
        __syncthreads();
        bf16x8 af = *(const bf16x8*)&As[(wave * 16 + l16) * 40 + quad * 8];
#pragma unroll
        for (int c = 0; c < 4; ++c) {
            bf16x8 bfr = *(const bf16x8*)&Bs[(c * 16 + l16) * 40 + quad * 8];
            acc[c] = __builtin_amdgcn_mfma_f32_16x16x32_bf16(af, bfr, acc[c], 0, 0, 0);
        }
    }
#pragma unroll
    for (int c = 0; c < 4; ++c)
#pragma unroll
        for (int r = 0; r < 4; ++r) {
            int gm = m0 + wave * 16 + quad * 4 + r;
            Out[(gm << 6) + c * 16 + l16] = acc[c][r];
        }
}

// ---------------------------------------------------------------------------
extern "C" void kernel_launch(void* const* d_in, const int* in_sizes, int n_in,
                              void* d_out, int out_size, void* d_ws, size_t ws_size,
                              hipStream_t stream) {
    const float* A    = (const float*)d_in[0];
    const float* Wqkv = (const float*)d_in[1];
    const float* Wout = (const float*)d_in[2];
    float* Out = (float*)d_out;

    short* ws = (short*)d_ws;
    short* Qb = ws;
    short* Kb = ws + 4194304;
    short* Vb = ws + 8388608;
    short* AO = ws + 12582912;

    dim3 g1(64, 48);
    hipLaunchKernelGGL(qkv_kernel, g1, dim3(256), 0, stream, A, Wqkv, Qb, Kb, Vb);
    dim3 g2(32, 32);
    hipLaunchKernelGGL(attn_kernel, g2, dim3(256), 0, stream, Qb, Kb, Vb, AO);
    hipLaunchKernelGGL(out_kernel, dim3(128), dim3(128), 0, stream, AO, Wout, Out);
}